// Round 2
// baseline (436.928 us; speedup 1.0000x reference)
//
#include <hip/hip_runtime.h>

// ---------------------------------------------------------------------------
// MultiHeadAttention (B=2, T=2048, D=1024, NH=16, hd=64) with ALiBi + causal.
// r2: swapped-operand barrier-free attention (P stays in registers via
// k-permutation cancellation); GEMMs use global_load_lds(16B) + both-sides
// XOR swizzle (m97/T2 pattern); V^T written via LDS tile transpose.
// ---------------------------------------------------------------------------

using f32x4  = __attribute__((ext_vector_type(4))) float;
using bf16x8 = __attribute__((ext_vector_type(8))) short;
typedef unsigned short u16;
using u16x4 = __attribute__((ext_vector_type(4))) u16;

#define T_SEQ  2048
#define NHEAD  16
#define HDIM   64
#define DMODEL 1024
#define MROWS  4096   // B*T

#define LOG2E 1.4426950408889634f

__device__ __forceinline__ u16 f2bf(float f) {
  union { float f; unsigned u; } v; v.f = f;
  return (u16)((v.u + 0x7fffu + ((v.u >> 16) & 1u)) >> 16);  // RNE
}

__device__ __forceinline__ void gl_lds16(const u16* g, u16* l) {
  __builtin_amdgcn_global_load_lds(
      (const __attribute__((address_space(1))) unsigned int*)g,
      (__attribute__((address_space(3))) unsigned int*)l, 16, 0, 0);
}

// ---------------------------------------------------------------------------
__global__ __launch_bounds__(256) void cvt_bf16(const float* __restrict__ src,
                                                u16* __restrict__ dst, int n) {
  int i = (blockIdx.x * 256 + threadIdx.x) * 4;
  if (i < n) {
    const float4 v = *reinterpret_cast<const float4*>(src + i);
    u16x4 o;
    o.x = f2bf(v.x); o.y = f2bf(v.y); o.z = f2bf(v.z); o.w = f2bf(v.w);
    *reinterpret_cast<u16x4*>(dst + i) = o;
  }
}

// ---------------------------------------------------------------------------
// Fused QKV projection: Y = x @ W^T + b (M=4096, N=1024, K=1024), bf16 MFMA.
// m97 structure: 128x128 tile, BK=64, global_load_lds(16) into linear LDS with
// pre-swizzled global source; ds_read applies the same XOR swizzle.
// z selects {Q,K,V}. Q scaled by D^-0.25 * log2e, K by D^-0.25. V -> V^T.
__global__ __launch_bounds__(256) void qkv_gemm(
    const u16* __restrict__ xb,
    const u16* __restrict__ wq, const u16* __restrict__ wk, const u16* __restrict__ wv,
    const float* __restrict__ bq, const float* __restrict__ bk, const float* __restrict__ bv,
    u16* __restrict__ q_ws, u16* __restrict__ k_ws, u16* __restrict__ vt_ws)
{
  const int K = DMODEL;
  const int z = blockIdx.z;
  const u16*   W    = (z == 0) ? wq : (z == 1) ? wk : wv;
  const float* bias = (z == 0) ? bq : (z == 1) ? bk : bv;
  const int bm = blockIdx.y, bn = blockIdx.x;
  const int tid = threadIdx.x;
  const int w = tid >> 6, lane = tid & 63, g = lane >> 4, c = lane & 15;
  const int wm = w >> 1, wn = w & 1;

  __shared__ u16 SM[2][128][64];  // linear (no pad) -- required by global_load_lds

  f32x4 zero4 = {0.f, 0.f, 0.f, 0.f};
  f32x4 acc[4][4];
#pragma unroll
  for (int m = 0; m < 4; ++m)
#pragma unroll
    for (int n = 0; n < 4; ++n) acc[m][n] = zero4;

  // stage indices (constant over K loop)
  int rr[4], cswz[4];
#pragma unroll
  for (int j = 0; j < 4; ++j) {
    int chunk = tid + 256 * j;
    rr[j] = chunk >> 3;                      // 0..127
    cswz[j] = ((chunk & 7) ^ (rr[j] & 7)) * 8;  // pre-swizzled source col (u16)
  }

  for (int k0 = 0; k0 < K; k0 += 64) {
#pragma unroll
    for (int j = 0; j < 4; ++j) {
      int chunk = tid + 256 * j;
      gl_lds16(xb + (size_t)(bm * 128 + rr[j]) * K + k0 + cswz[j],
               &SM[0][0][0] + chunk * 8);
      gl_lds16(W + (size_t)(bn * 128 + rr[j]) * K + k0 + cswz[j],
               &SM[1][0][0] + chunk * 8);
    }
    __syncthreads();
#pragma unroll
    for (int kk = 0; kk < 2; ++kk) {
      bf16x8 af[4], bfr[4];
#pragma unroll
      for (int m = 0; m < 4; ++m) {
        int row = wm * 64 + m * 16 + c;
        af[m] = *reinterpret_cast<const bf16x8*>(
            &SM[0][row][(kk * 32 + g * 8) ^ ((row & 7) * 8)]);
      }
#pragma unroll
      for (int n = 0; n < 4; ++n) {
        int row = wn * 64 + n * 16 + c;
        bfr[n] = *reinterpret_cast<const bf16x8*>(
            &SM[1][row][(kk * 32 + g * 8) ^ ((row & 7) * 8)]);
      }
#pragma unroll
      for (int m = 0; m < 4; ++m)
#pragma unroll
        for (int n = 0; n < 4; ++n)
          acc[m][n] = __builtin_amdgcn_mfma_f32_16x16x32_bf16(af[m], bfr[n], acc[m][n], 0, 0, 0);
    }
    __syncthreads();
  }

  const float rs = 0.1767766953f;          // 1024^-0.25
  const float qs = rs * LOG2E;             // fold log2e into Q for exp2 softmax

  if (z == 2) {
    // V: bias add, then transpose 128x128 tile via LDS -> coalesced V^T stores
    u16* tr = &SM[0][0][0];  // overlay: needs 64*136 = 8704 u16 <= 16384
    const int bb = (bm * 128) >> 11;          // batch (tile never spans batches)
    const int t_base = (bm * 128) & (T_SEQ - 1);
#pragma unroll
    for (int hh = 0; hh < 2; ++hh) {
      __syncthreads();
      if (wn == hh) {
#pragma unroll
        for (int n = 0; n < 4; ++n) {
          float bv_ = bias[bn * 128 + wn * 64 + n * 16 + c];
#pragma unroll
          for (int m = 0; m < 4; ++m) {
#pragma unroll
            for (int i = 0; i < 4; ++i) {
              tr[(n * 16 + c) * 136 + wm * 64 + m * 16 + g * 4 + i] =
                  f2bf(acc[m][n][i] + bv_);
            }
          }
        }
      }
      __syncthreads();
#pragma unroll
      for (int rep = 0; rep < 4; ++rep) {
        int idx = tid + rep * 256;            // 0..1023
        int dr = idx >> 4, ch = idx & 15;
        bf16x8 vv = *reinterpret_cast<const bf16x8*>(&tr[dr * 136 + ch * 8]);
        int d_glob = bn * 128 + hh * 64 + dr;
        int head = d_glob >> 6, dd = d_glob & 63;
        *reinterpret_cast<bf16x8*>(
            vt_ws + (((size_t)(bb * NHEAD + head) * HDIM + dd) * T_SEQ) + t_base + ch * 8) = vv;
      }
    }
  } else {
    u16* dst = (z == 0) ? q_ws : k_ws;
    const float sc = (z == 0) ? qs : rs;
#pragma unroll
    for (int m = 0; m < 4; ++m) {
      int mrow_base = bm * 128 + wm * 64 + m * 16 + g * 4;
#pragma unroll
      for (int n = 0; n < 4; ++n) {
        int n_idx = bn * 128 + wn * 64 + n * 16 + c;
        float bv_ = bias[n_idx];
        int head = n_idx >> 6, d = n_idx & 63;
#pragma unroll
        for (int i = 0; i < 4; ++i) {
          int mrow = mrow_base + i;
          int b = mrow >> 11, t = mrow & (T_SEQ - 1);
          dst[((size_t)(b * NHEAD + head) * T_SEQ + t) * HDIM + d] =
              f2bf((acc[m][n][i] + bv_) * sc);
        }
      }
    }
  }
}

// ---------------------------------------------------------------------------
// Flash attention, swapped-operand form. Grid (T/64 reversed, B*NH), 4 waves,
// each wave owns 16 q rows. No LDS, no barriers: QK^T computed as mfma(K,Q)
// so scores land q-major per lane (q = lane&15); PV uses the identical
// k-permutation on P (in-register) and V (permuted loads), which cancels.
__global__ __launch_bounds__(256) void attn_fused(
    const u16* __restrict__ Q, const u16* __restrict__ Kk,
    const u16* __restrict__ VT, u16* __restrict__ O)
{
  const int w = threadIdx.x >> 6;
  const int lane = threadIdx.x & 63;
  const int g = lane >> 4, c = lane & 15;
  const int qb = gridDim.x - 1 - blockIdx.x;   // heavy blocks first
  const int q0 = qb * 64;
  const int bh = blockIdx.y;
  const int h = bh & (NHEAD - 1), b = bh >> 4;
  const float slope2 = __builtin_amdgcn_exp2f(-0.5f * (float)(h + 1)) * LOG2E;
  const u16* Qp = Q  + (size_t)bh * T_SEQ * HDIM;
  const u16* Kp = Kk + (size_t)bh * T_SEQ * HDIM;
  const u16* Vp = VT + (size_t)bh * HDIM * T_SEQ;
  const int qrow = q0 + w * 16;

  bf16x8 qf0 = *reinterpret_cast<const bf16x8*>(Qp + (size_t)(qrow + c) * HDIM + g * 8);
  bf16x8 qf1 = *reinterpret_cast<const bf16x8*>(Qp + (size_t)(qrow + c) * HDIM + 32 + g * 8);

  f32x4 zero4 = {0.f, 0.f, 0.f, 0.f};
  f32x4 o[4];
#pragma unroll
  for (int dg = 0; dg < 4; ++dg) o[dg] = zero4;
  float mrun = -3.0e38f, lrun = 0.f;

  for (int kv0 = 0; kv0 <= q0; kv0 += 64) {
    // --- QK^T (swapped): s[jj] = C[kv 16-block jj][q], lane: q=c, kv=4g+i ---
    f32x4 s[4];
#pragma unroll
    for (int jj = 0; jj < 4; ++jj) {
      const u16* kr = Kp + (size_t)(kv0 + jj * 16 + c) * HDIM;
      bf16x8 k0 = *reinterpret_cast<const bf16x8*>(kr + g * 8);
      bf16x8 k1 = *reinterpret_cast<const bf16x8*>(kr + 32 + g * 8);
      f32x4 z4 = zero4;
      z4 = __builtin_amdgcn_mfma_f32_16x16x32_bf16(k0, qf0, z4, 0, 0, 0);
      z4 = __builtin_amdgcn_mfma_f32_16x16x32_bf16(k1, qf1, z4, 0, 0, 0);
      s[jj] = z4;
    }

    // --- issue V loads early (latency hidden under softmax VALU) ---
    // k-slot (g,r) of PV maps to kv = 16*(r>>2) + 4g + (r&3); same sigma on P.
    short4 va[4][4];
#pragma unroll
    for (int dg = 0; dg < 4; ++dg) {
      const u16* vr = Vp + (size_t)(dg * 16 + c) * T_SEQ + kv0 + 4 * g;
      va[dg][0] = *reinterpret_cast<const short4*>(vr);
      va[dg][1] = *reinterpret_cast<const short4*>(vr + 16);
      va[dg][2] = *reinterpret_cast<const short4*>(vr + 32);
      va[dg][3] = *reinterpret_cast<const short4*>(vr + 48);
    }

    // --- softmax (log2-domain; scores already scaled by log2e via Q) ---
    const bool edge = (kv0 == q0);
    const int kbase = kv0 + 4 * g - (qrow + c);   // kv - q for (jj=0,i=0)
    float mt = -3.0e38f;
#pragma unroll
    for (int jj = 0; jj < 4; ++jj) {
#pragma unroll
      for (int i = 0; i < 4; ++i) {
        int rel = kbase + 16 * jj + i;
        float sv = s[jj][i] + slope2 * (float)rel;
        if (edge && rel > 0) sv = -3.0e38f;
        s[jj][i] = sv;
        mt = fmaxf(mt, sv);
      }
    }
    mt = fmaxf(mt, __shfl_xor(mt, 16, 64));
    mt = fmaxf(mt, __shfl_xor(mt, 32, 64));
    float mnew = fmaxf(mrun, mt);
    float alpha = __builtin_amdgcn_exp2f(mrun - mnew);
    mrun = mnew;

    float rsum = 0.f;
    u16 pb[16];
#pragma unroll
    for (int jj = 0; jj < 4; ++jj) {
#pragma unroll
      for (int i = 0; i < 4; ++i) {
        float p = __builtin_amdgcn_exp2f(s[jj][i] - mrun);
        rsum += p;
        pb[jj * 4 + i] = f2bf(p);
      }
    }
    rsum += __shfl_xor(rsum, 16, 64);
    rsum += __shfl_xor(rsum, 32, 64);
    lrun = lrun * alpha + rsum;

    // rescale o (alpha belongs to row q=c; o rows are q=g*4+i -> broadcast)
    float ar[4];
#pragma unroll
    for (int i = 0; i < 4; ++i) ar[i] = __shfl(alpha, g * 4 + i, 64);
#pragma unroll
    for (int dg = 0; dg < 4; ++dg)
#pragma unroll
      for (int i = 0; i < 4; ++i) o[dg][i] *= ar[i];

    // --- PV: o[dg] += P * V, permuted-k on both operands ---
    bf16x8 pa0, pa1;
#pragma unroll
    for (int r = 0; r < 8; ++r) { pa0[r] = (short)pb[r]; pa1[r] = (short)pb[8 + r]; }
#pragma unroll
    for (int dg = 0; dg < 4; ++dg) {
      bf16x8 vf0, vf1;
#pragma unroll
      for (int e = 0; e < 4; ++e) {
        vf0[e]     = va[dg][0][e]; vf0[4 + e] = va[dg][1][e];
        vf1[e]     = va[dg][2][e]; vf1[4 + e] = va[dg][3][e];
      }
      o[dg] = __builtin_amdgcn_mfma_f32_16x16x32_bf16(pa0, vf0, o[dg], 0, 0, 0);
      o[dg] = __builtin_amdgcn_mfma_f32_16x16x32_bf16(pa1, vf1, o[dg], 0, 0, 0);
    }
  }

  // epilogue: divide by l (per output row q = g*4+i) and store
  float rl[4];
#pragma unroll
  for (int i = 0; i < 4; ++i) {
    float li = __shfl(lrun, g * 4 + i, 64);
    rl[i] = 1.0f / li;
  }
#pragma unroll
  for (int dg = 0; dg < 4; ++dg) {
#pragma unroll
    for (int i = 0; i < 4; ++i) {
      int qi = qrow + g * 4 + i;
      O[((size_t)b * T_SEQ + qi) * DMODEL + h * HDIM + dg * 16 + c] =
          f2bf(o[dg][i] * rl[i]);
    }
  }
}

// ---------------------------------------------------------------------------
// Output projection: out = ao @ Wp^T + bp (fp32 out). Same m97 GEMM core.
__global__ __launch_bounds__(256) void out_gemm(
    const u16* __restrict__ ao, const u16* __restrict__ wp,
    const float* __restrict__ bp, float* __restrict__ out)
{
  const int K = DMODEL;
  const int bm = blockIdx.y, bn = blockIdx.x;
  const int tid = threadIdx.x;
  const int w = tid >> 6, lane = tid & 63, g = lane >> 4, c = lane & 15;
  const int wm = w >> 1, wn = w & 1;

  __shared__ u16 SM[2][128][64];

  f32x4 zero4 = {0.f, 0.f, 0.f, 0.f};
  f32x4 acc[4][4];
#pragma unroll
  for (int m = 0; m < 4; ++m)
#pragma unroll
    for (int n = 0; n < 4; ++n) acc[m][n] = zero4;

  int rr[4], cswz[4];
#pragma unroll
  for (int j = 0; j < 4; ++j) {
    int chunk = tid + 256 * j;
    rr[j] = chunk >> 3;
    cswz[j] = ((chunk & 7) ^ (rr[j] & 7)) * 8;
  }

  for (int k0 = 0; k0 < K; k0 += 64) {
#pragma unroll
    for (int j = 0; j < 4; ++j) {
      int chunk = tid + 256 * j;
      gl_lds16(ao + (size_t)(bm * 128 + rr[j]) * K + k0 + cswz[j],
               &SM[0][0][0] + chunk * 8);
      gl_lds16(wp + (size_t)(bn * 128 + rr[j]) * K + k0 + cswz[j],
               &SM[1][0][0] + chunk * 8);
    }
    __syncthreads();
#pragma unroll
    for (int kk = 0; kk < 2; ++kk) {
      bf16x8 af[4], bfr[4];
#pragma unroll
      for (int m = 0; m < 4; ++m) {
        int row = wm * 64 + m * 16 + c;
        af[m] = *reinterpret_cast<const bf16x8*>(
            &SM[0][row][(kk * 32 + g * 8) ^ ((row & 7) * 8)]);
      }
#pragma unroll
      for (int n = 0; n < 4; ++n) {
        int row = wn * 64 + n * 16 + c;
        bfr[n] = *reinterpret_cast<const bf16x8*>(
            &SM[1][row][(kk * 32 + g * 8) ^ ((row & 7) * 8)]);
      }
#pragma unroll
      for (int m = 0; m < 4; ++m)
#pragma unroll
        for (int n = 0; n < 4; ++n)
          acc[m][n] = __builtin_amdgcn_mfma_f32_16x16x32_bf16(af[m], bfr[n], acc[m][n], 0, 0, 0);
    }
    __syncthreads();
  }

#pragma unroll
  for (int m = 0; m < 4; ++m) {
    int mrow_base = bm * 128 + wm * 64 + m * 16 + g * 4;
#pragma unroll
    for (int n = 0; n < 4; ++n) {
      int n_idx = bn * 128 + wn * 64 + n * 16 + c;
      float bv_ = bp[n_idx];
#pragma unroll
      for (int i = 0; i < 4; ++i) {
        int mrow = mrow_base + i;
        out[(size_t)mrow * DMODEL + n_idx] = acc[m][n][i] + bv_;
      }
    }
  }
}

// ---------------------------------------------------------------------------
extern "C" void kernel_launch(void* const* d_in, const int* in_sizes, int n_in,
                              void* d_out, int out_size, void* d_ws, size_t ws_size,
                              hipStream_t stream) {
  const float* x  = (const float*)d_in[0];
  const float* Wq = (const float*)d_in[1];
  const float* bq = (const float*)d_in[2];
  const float* Wk = (const float*)d_in[3];
  const float* bk = (const float*)d_in[4];
  const float* Wv = (const float*)d_in[5];
  const float* bv = (const float*)d_in[6];
  const float* Wp = (const float*)d_in[7];
  const float* bp = (const float*)d_in[8];
  float* out = (float*)d_out;

  // workspace layout (u16 elements): ~48 MB total
  u16* ws    = (u16*)d_ws;
  u16* xb    = ws;                       // 4,194,304  (x as bf16)
  u16* wqb   = xb   + 4194304;           // 1,048,576
  u16* wkb   = wqb  + 1048576;
  u16* wvb   = wkb  + 1048576;
  u16* wpb   = wvb  + 1048576;
  u16* q_ws  = wpb  + 1048576;           // [B,NH,T,hd]  (scaled by rs*log2e)
  u16* k_ws  = q_ws + 4194304;           // [B,NH,T,hd]  (scaled by rs)
  u16* vt_ws = k_ws + 4194304;           // [B,NH,hd,T]
  u16* ao    = vt_ws + 4194304;          // [B,T,D] attention output

  cvt_bf16<<<4096, 256, 0, stream>>>(x,  xb,  4194304);
  cvt_bf16<<<1024, 256, 0, stream>>>(Wq, wqb, 1048576);
  cvt_bf16<<<1024, 256, 0, stream>>>(Wk, wkb, 1048576);
  cvt_bf16<<<1024, 256, 0, stream>>>(Wv, wvb, 1048576);
  cvt_bf16<<<1024, 256, 0, stream>>>(Wp, wpb, 1048576);

  qkv_gemm<<<dim3(DMODEL / 128, MROWS / 128, 3), 256, 0, stream>>>(
      xb, wqb, wkb, wvb, bq, bk, bv, q_ws, k_ws, vt_ws);

  attn_fused<<<dim3(T_SEQ / 64, 2 * NHEAD), 256, 0, stream>>>(q_ws, k_ws, vt_ws, ao);

  out_gemm<<<dim3(DMODEL / 128, MROWS / 128), 256, 0, stream>>>(ao, wpb, bp, out);
}

// Round 3
// 172.903 us; speedup vs baseline: 2.5270x; 2.5270x over previous
//
#include <hip/hip_runtime.h>

// ---------------------------------------------------------------------------
// MultiHeadAttention (B=2, T=2048, D=1024, NH=16, hd=64) with ALiBi + causal.
// r3: attention keeps swapped-operand register softmax (r2) but stages K/V
// tiles in LDS via global_load_lds(16B) + XOR swizzle, shared across 4 waves,
// double-buffered 2-phase schedule (stage t+1 issued before compute t, one
// barrier per tile). KV iterated descending -> defer-max rescale skip (T13).
// GEMMs unchanged m97 structure (global_load_lds + both-sides swizzle).
// ---------------------------------------------------------------------------

using f32x4  = __attribute__((ext_vector_type(4))) float;
using bf16x8 = __attribute__((ext_vector_type(8))) short;
typedef unsigned short u16;
using u16x4 = __attribute__((ext_vector_type(4))) u16;
using u32x4 = __attribute__((ext_vector_type(4))) unsigned int;

#define T_SEQ  2048
#define NHEAD  16
#define HDIM   64
#define DMODEL 1024
#define MROWS  4096   // B*T

#define LOG2E 1.4426950408889634f

__device__ __forceinline__ u16 f2bf(float f) {
  union { float f; unsigned u; } v; v.f = f;
  return (u16)((v.u + 0x7fffu + ((v.u >> 16) & 1u)) >> 16);  // RNE
}

__device__ __forceinline__ unsigned cvt_pk_bf16(float lo, float hi) {
  unsigned r;
  asm("v_cvt_pk_bf16_f32 %0, %1, %2" : "=v"(r) : "v"(lo), "v"(hi));
  return r;
}

__device__ __forceinline__ void gl_lds16(const u16* g, u16* l) {
  __builtin_amdgcn_global_load_lds(
      (const __attribute__((address_space(1))) unsigned int*)g,
      (__attribute__((address_space(3))) unsigned int*)l, 16, 0, 0);
}

// ---------------------------------------------------------------------------
__global__ __launch_bounds__(256) void cvt_bf16(const float* __restrict__ src,
                                                u16* __restrict__ dst, int n) {
  int i = (blockIdx.x * 256 + threadIdx.x) * 4;
  if (i < n) {
    const float4 v = *reinterpret_cast<const float4*>(src + i);
    u16x4 o;
    o.x = f2bf(v.x); o.y = f2bf(v.y); o.z = f2bf(v.z); o.w = f2bf(v.w);
    *reinterpret_cast<u16x4*>(dst + i) = o;
  }
}

// all four weights are 1M elements; dst regions contiguous
__global__ __launch_bounds__(256) void cvt_w4(
    const float* __restrict__ w0, const float* __restrict__ w1,
    const float* __restrict__ w2, const float* __restrict__ w3,
    u16* __restrict__ dst) {
  const float* src = (blockIdx.y == 0) ? w0 : (blockIdx.y == 1) ? w1
                   : (blockIdx.y == 2) ? w2 : w3;
  u16* d = dst + (size_t)blockIdx.y * 1048576;
  int i = (blockIdx.x * 256 + threadIdx.x) * 4;
  const float4 v = *reinterpret_cast<const float4*>(src + i);
  u16x4 o;
  o.x = f2bf(v.x); o.y = f2bf(v.y); o.z = f2bf(v.z); o.w = f2bf(v.w);
  *reinterpret_cast<u16x4*>(d + i) = o;
}

// ---------------------------------------------------------------------------
// Fused QKV projection (m97 structure, unchanged from r2 -- verified).
__global__ __launch_bounds__(256) void qkv_gemm(
    const u16* __restrict__ xb,
    const u16* __restrict__ wq, const u16* __restrict__ wk, const u16* __restrict__ wv,
    const float* __restrict__ bq, const float* __restrict__ bk, const float* __restrict__ bv,
    u16* __restrict__ q_ws, u16* __restrict__ k_ws, u16* __restrict__ vt_ws)
{
  const int K = DMODEL;
  const int z = blockIdx.z;
  const u16*   W    = (z == 0) ? wq : (z == 1) ? wk : wv;
  const float* bias = (z == 0) ? bq : (z == 1) ? bk : bv;
  const int bm = blockIdx.y, bn = blockIdx.x;
  const int tid = threadIdx.x;
  const int w = tid >> 6, lane = tid & 63, g = lane >> 4, c = lane & 15;
  const int wm = w >> 1, wn = w & 1;

  __shared__ u16 SM[2][128][64];

  f32x4 zero4 = {0.f, 0.f, 0.f, 0.f};
  f32x4 acc[4][4];
#pragma unroll
  for (int m = 0; m < 4; ++m)
#pragma unroll
    for (int n = 0; n < 4; ++n) acc[m][n] = zero4;

  int rr[4], cswz[4];
#pragma unroll
  for (int j = 0; j < 4; ++j) {
    int chunk = tid + 256 * j;
    rr[j] = chunk >> 3;
    cswz[j] = ((chunk & 7) ^ (rr[j] & 7)) * 8;
  }

  for (int k0 = 0; k0 < K; k0 += 64) {
#pragma unroll
    for (int j = 0; j < 4; ++j) {
      int chunk = tid + 256 * j;
      gl_lds16(xb + (size_t)(bm * 128 + rr[j]) * K + k0 + cswz[j],
               &SM[0][0][0] + chunk * 8);
      gl_lds16(W + (size_t)(bn * 128 + rr[j]) * K + k0 + cswz[j],
               &SM[1][0][0] + chunk * 8);
    }
    __syncthreads();
#pragma unroll
    for (int kk = 0; kk < 2; ++kk) {
      bf16x8 af[4], bfr[4];
#pragma unroll
      for (int m = 0; m < 4; ++m) {
        int row = wm * 64 + m * 16 + c;
        af[m] = *reinterpret_cast<const bf16x8*>(
            &SM[0][row][(kk * 32 + g * 8) ^ ((row & 7) * 8)]);
      }
#pragma unroll
      for (int n = 0; n < 4; ++n) {
        int row = wn * 64 + n * 16 + c;
        bfr[n] = *reinterpret_cast<const bf16x8*>(
            &SM[1][row][(kk * 32 + g * 8) ^ ((row & 7) * 8)]);
      }
#pragma unroll
      for (int m = 0; m < 4; ++m)
#pragma unroll
        for (int n = 0; n < 4; ++n)
          acc[m][n] = __builtin_amdgcn_mfma_f32_16x16x32_bf16(af[m], bfr[n], acc[m][n], 0, 0, 0);
    }
    __syncthreads();
  }

  const float rs = 0.1767766953f;          // 1024^-0.25
  const float qs = rs * LOG2E;

  if (z == 2) {
    u16* tr = &SM[0][0][0];
    const int bb = (bm * 128) >> 11;
    const int t_base = (bm * 128) & (T_SEQ - 1);
#pragma unroll
    for (int hh = 0; hh < 2; ++hh) {
      __syncthreads();
      if (wn == hh) {
#pragma unroll
        for (int n = 0; n < 4; ++n) {
          float bv_ = bias[bn * 128 + wn * 64 + n * 16 + c];
#pragma unroll
          for (int m = 0; m < 4; ++m) {
#pragma unroll
            for (int i = 0; i < 4; ++i) {
              tr[(n * 16 + c) * 136 + wm * 64 + m * 16 + g * 4 + i] =
                  f2bf(acc[m][n][i] + bv_);
            }
          }
        }
      }
      __syncthreads();
#pragma unroll
      for (int rep = 0; rep < 4; ++rep) {
        int idx = tid + rep * 256;
        int dr = idx >> 4, ch = idx & 15;
        bf16x8 vv = *reinterpret_cast<const bf16x8*>(&tr[dr * 136 + ch * 8]);
        int d_glob = bn * 128 + hh * 64 + dr;
        int head = d_glob >> 6, dd = d_glob & 63;
        *reinterpret_cast<bf16x8*>(
            vt_ws + (((size_t)(bb * NHEAD + head) * HDIM + dd) * T_SEQ) + t_base + ch * 8) = vv;
      }
    }
  } else {
    u16* dst = (z == 0) ? q_ws : k_ws;
    const float sc = (z == 0) ? qs : rs;
#pragma unroll
    for (int m = 0; m < 4; ++m) {
      int mrow_base = bm * 128 + wm * 64 + m * 16 + g * 4;
#pragma unroll
      for (int n = 0; n < 4; ++n) {
        int n_idx = bn * 128 + wn * 64 + n * 16 + c;
        float bv_ = bias[n_idx];
        int head = n_idx >> 6, d = n_idx & 63;
#pragma unroll
        for (int i = 0; i < 4; ++i) {
          int mrow = mrow_base + i;
          int b = mrow >> 11, t = mrow & (T_SEQ - 1);
          dst[((size_t)(b * NHEAD + head) * T_SEQ + t) * HDIM + d] =
              f2bf((acc[m][n][i] + bv_) * sc);
        }
      }
    }
  }
}

// ---------------------------------------------------------------------------
// Flash attention r3: LDS-staged K/V (double-buffered, XOR-swizzled), swapped
// QK^T register softmax, descending KV order + defer-max rescale skip.
__global__ __launch_bounds__(256, 4) void attn_fused(
    const u16* __restrict__ Q, const u16* __restrict__ Kk,
    const u16* __restrict__ VT, u16* __restrict__ O)
{
  const int tid = threadIdx.x;
  const int w = tid >> 6;
  const int lane = tid & 63;
  const int g = lane >> 4, c = lane & 15;
  const int qb = gridDim.x - 1 - blockIdx.x;   // heavy blocks first
  const int q0 = qb * 64;
  const int bh = blockIdx.y;
  const int h = bh & (NHEAD - 1), b = bh >> 4;
  const float slope2 = exp2f(-0.5f * (float)(h + 1)) * LOG2E;
  const u16* Qp = Q  + (size_t)bh * T_SEQ * HDIM;
  const u16* Kp = Kk + (size_t)bh * T_SEQ * HDIM;
  const u16* Vp = VT + (size_t)bh * HDIM * T_SEQ;
  const int qrow = q0 + w * 16;

  __shared__ u16 KB[2][64][64];
  __shared__ u16 VB[2][64][64];

  bf16x8 qf0 = *reinterpret_cast<const bf16x8*>(Qp + (size_t)(qrow + c) * HDIM + g * 8);
  bf16x8 qf1 = *reinterpret_cast<const bf16x8*>(Qp + (size_t)(qrow + c) * HDIM + 32 + g * 8);

  // staging geometry: chunk = tid (+256), row = chunk>>3, swizzled col source
  const int s_r0 = tid >> 3;          // 0..31
  const int s_r1 = s_r0 + 32;         // 32..63 ((s_r1&7)==(s_r0&7))
  const int s_c0 = ((tid & 7) ^ (s_r0 & 7)) * 8;

  const int nt = qb + 1;

  // prologue: stage tile 0 (kv0 = q0, the diagonal tile) into buffer 0
  {
    u16* kb = &KB[0][0][0]; u16* vb = &VB[0][0][0];
    gl_lds16(Kp + (size_t)(q0 + s_r0) * HDIM + s_c0, kb + tid * 8);
    gl_lds16(Kp + (size_t)(q0 + s_r1) * HDIM + s_c0, kb + (tid + 256) * 8);
    gl_lds16(Vp + (size_t)s_r0 * T_SEQ + q0 + s_c0, vb + tid * 8);
    gl_lds16(Vp + (size_t)s_r1 * T_SEQ + q0 + s_c0, vb + (tid + 256) * 8);
  }
  __syncthreads();

  f32x4 zero4 = {0.f, 0.f, 0.f, 0.f};
  f32x4 o[4];
#pragma unroll
  for (int dg = 0; dg < 4; ++dg) o[dg] = zero4;
  float mrun = -3.0e38f, lrun = 0.f;

  for (int t = 0; t < nt; ++t) {
    const u16* kb = &KB[t & 1][0][0];
    const u16* vb = &VB[t & 1][0][0];

    // issue next-tile stage (in flight during this tile's compute)
    if (t + 1 < nt) {
      const int kvn = (nt - 2 - t) * 64;
      u16* kbn = &KB[(t + 1) & 1][0][0];
      u16* vbn = &VB[(t + 1) & 1][0][0];
      gl_lds16(Kp + (size_t)(kvn + s_r0) * HDIM + s_c0, kbn + tid * 8);
      gl_lds16(Kp + (size_t)(kvn + s_r1) * HDIM + s_c0, kbn + (tid + 256) * 8);
      gl_lds16(Vp + (size_t)s_r0 * T_SEQ + kvn + s_c0, vbn + tid * 8);
      gl_lds16(Vp + (size_t)s_r1 * T_SEQ + kvn + s_c0, vbn + (tid + 256) * 8);
    }

    const int kv0 = (nt - 1 - t) * 64;

    // --- QK^T (swapped): lane holds q=c, kv = 16jj + 4g + i ---
    f32x4 s[4];
#pragma unroll
    for (int jj = 0; jj < 4; ++jj) {
      const int r = jj * 16 + c;
      bf16x8 k0 = *reinterpret_cast<const bf16x8*>(kb + r * 64 + ((g ^ (r & 7)) * 8));
      bf16x8 k1 = *reinterpret_cast<const bf16x8*>(kb + r * 64 + (((4 + g) ^ (r & 7)) * 8));
      f32x4 z4 = zero4;
      z4 = __builtin_amdgcn_mfma_f32_16x16x32_bf16(k0, qf0, z4, 0, 0, 0);
      z4 = __builtin_amdgcn_mfma_f32_16x16x32_bf16(k1, qf1, z4, 0, 0, 0);
      s[jj] = z4;
    }

    // --- ALiBi bias (+ causal mask only on the diagonal tile t==0) ---
    const int kbase = kv0 + 4 * g - (qrow + c);   // kv - q at (jj=0,i=0)
    float mt = -3.0e38f;
    if (t == 0) {
#pragma unroll
      for (int jj = 0; jj < 4; ++jj)
#pragma unroll
        for (int i = 0; i < 4; ++i) {
          int rel = kbase + 16 * jj + i;
          float sv = s[jj][i] + slope2 * (float)rel;
          if (rel > 0) sv = -3.0e38f;
          s[jj][i] = sv;
          mt = fmaxf(mt, sv);
        }
    } else {
#pragma unroll
      for (int jj = 0; jj < 4; ++jj)
#pragma unroll
        for (int i = 0; i < 4; ++i) {
          float sv = s[jj][i] + slope2 * (float)(kbase + 16 * jj + i);
          s[jj][i] = sv;
          mt = fmaxf(mt, sv);
        }
    }
    mt = fmaxf(mt, __shfl_xor(mt, 16, 64));
    mt = fmaxf(mt, __shfl_xor(mt, 32, 64));

    // --- defer-max (T13): skip rescale while mt <= mrun + 8 nats ---
    if (!__all(mt <= mrun + 11.5416f)) {
      float mnew = fmaxf(mrun, mt);
      float alpha = __builtin_amdgcn_exp2f(mrun - mnew);
      mrun = mnew;
      lrun *= alpha;
      float ar[4];
#pragma unroll
      for (int i = 0; i < 4; ++i) ar[i] = __shfl(alpha, g * 4 + i, 64);
#pragma unroll
      for (int dg = 0; dg < 4; ++dg)
#pragma unroll
        for (int i = 0; i < 4; ++i) o[dg][i] *= ar[i];
    }

    // --- P = exp2(s - mrun), row-sum, pack to bf16 (cvt_pk) ---
    float p[16];
    float rsum = 0.f;
#pragma unroll
    for (int jj = 0; jj < 4; ++jj)
#pragma unroll
      for (int i = 0; i < 4; ++i) {
        float e = __builtin_amdgcn_exp2f(s[jj][i] - mrun);
        rsum += e;
        p[jj * 4 + i] = e;
      }
    union { bf16x8 v; u32x4 u; } P0, P1;
#pragma unroll
    for (int k = 0; k < 4; ++k) {
      P0.u[k] = cvt_pk_bf16(p[2 * k], p[2 * k + 1]);
      P1.u[k] = cvt_pk_bf16(p[8 + 2 * k], p[8 + 2 * k + 1]);
    }
    rsum += __shfl_xor(rsum, 16, 64);
    rsum += __shfl_xor(rsum, 32, 64);
    lrun += rsum;

    // --- PV: V fragments from swizzled LDS (permuted-k matches P layout) ---
#pragma unroll
    for (int dg = 0; dg < 4; ++dg) {
      const int vr = dg * 16 + c;
      const int vbase = vr * 64 + (g & 1) * 4;
      const int sw = vr & 7;
      short4 a0 = *reinterpret_cast<const short4*>(vb + vbase + (((g >> 1) + 0) ^ sw) * 8);
      short4 a1 = *reinterpret_cast<const short4*>(vb + vbase + (((g >> 1) + 2) ^ sw) * 8);
      short4 a2 = *reinterpret_cast<const short4*>(vb + vbase + (((g >> 1) + 4) ^ sw) * 8);
      short4 a3 = *reinterpret_cast<const short4*>(vb + vbase + (((g >> 1) + 6) ^ sw) * 8);
      bf16x8 vf0, vf1;
#pragma unroll
      for (int e = 0; e < 4; ++e) {
        vf0[e] = a0[e]; vf0[4 + e] = a1[e];
        vf1[e] = a2[e]; vf1[4 + e] = a3[e];
      }
      o[dg] = __builtin_amdgcn_mfma_f32_16x16x32_bf16(P0.v, vf0, o[dg], 0, 0, 0);
      o[dg] = __builtin_amdgcn_mfma_f32_16x16x32_bf16(P1.v, vf1, o[dg], 0, 0, 0);
    }

    __syncthreads();   // drains stage(t+1) [vmcnt] + our ds_reads [lgkmcnt]
  }

  // epilogue: divide by l (per output row q = g*4+i) and store
  float rl[4];
#pragma unroll
  for (int i = 0; i < 4; ++i) {
    float li = __shfl(lrun, g * 4 + i, 64);
    rl[i] = 1.0f / li;
  }
#pragma unroll
  for (int dg = 0; dg < 4; ++dg) {
#pragma unroll
    for (int i = 0; i < 4; ++i) {
      int qi = qrow + g * 4 + i;
      O[((size_t)b * T_SEQ + qi) * DMODEL + h * HDIM + dg * 16 + c] =
          f2bf(o[dg][i] * rl[i]);
    }
  }
}

// ---------------------------------------------------------------------------
// Output projection: out = ao @ Wp^T + bp (fp32 out). m97 GEMM core.
__global__ __launch_bounds__(256) void out_gemm(
    const u16* __restrict__ ao, const u16* __restrict__ wp,
    const float* __restrict__ bp, float* __restrict__ out)
{
  const int K = DMODEL;
  const int bm = blockIdx.y, bn = blockIdx.x;
  const int tid = threadIdx.x;
  const int w = tid >> 6, lane = tid & 63, g = lane >> 4, c = lane & 15;
  const int wm = w >> 1, wn = w & 1;

  __shared__ u16 SM[2][128][64];

  f32x4 zero4 = {0.f, 0.f, 0.f, 0.f};
  f32x4 acc[4][4];
#pragma unroll
  for (int m = 0; m < 4; ++m)
#pragma unroll
    for (int n = 0; n < 4; ++n) acc[m][n] = zero4;

  int rr[4], cswz[4];
#pragma unroll
  for (int j = 0; j < 4; ++j) {
    int chunk = tid + 256 * j;
    rr[j] = chunk >> 3;
    cswz[j] = ((chunk & 7) ^ (rr[j] & 7)) * 8;
  }

  for (int k0 = 0; k0 < K; k0 += 64) {
#pragma unroll
    for (int j = 0; j < 4; ++j) {
      int chunk = tid + 256 * j;
      gl_lds16(ao + (size_t)(bm * 128 + rr[j]) * K + k0 + cswz[j],
               &SM[0][0][0] + chunk * 8);
      gl_lds16(wp + (size_t)(bn * 128 + rr[j]) * K + k0 + cswz[j],
               &SM[1][0][0] + chunk * 8);
    }
    __syncthreads();
#pragma unroll
    for (int kk = 0; kk < 2; ++kk) {
      bf16x8 af[4], bfr[4];
#pragma unroll
      for (int m = 0; m < 4; ++m) {
        int row = wm * 64 + m * 16 + c;
        af[m] = *reinterpret_cast<const bf16x8*>(
            &SM[0][row][(kk * 32 + g * 8) ^ ((row & 7) * 8)]);
      }
#pragma unroll
      for (int n = 0; n < 4; ++n) {
        int row = wn * 64 + n * 16 + c;
        bfr[n] = *reinterpret_cast<const bf16x8*>(
            &SM[1][row][(kk * 32 + g * 8) ^ ((row & 7) * 8)]);
      }
#pragma unroll
      for (int m = 0; m < 4; ++m)
#pragma unroll
        for (int n = 0; n < 4; ++n)
          acc[m][n] = __builtin_amdgcn_mfma_f32_16x16x32_bf16(af[m], bfr[n], acc[m][n], 0, 0, 0);
    }
    __syncthreads();
  }

#pragma unroll
  for (int m = 0; m < 4; ++m) {
    int mrow_base = bm * 128 + wm * 64 + m * 16 + g * 4;
#pragma unroll
    for (int n = 0; n < 4; ++n) {
      int n_idx = bn * 128 + wn * 64 + n * 16 + c;
      float bv_ = bp[n_idx];
#pragma unroll
      for (int i = 0; i < 4; ++i) {
        int mrow = mrow_base + i;
        out[(size_t)mrow * DMODEL + n_idx] = acc[m][n][i] + bv_;
      }
    }
  }
}

// ---------------------------------------------------------------------------
extern "C" void kernel_launch(void* const* d_in, const int* in_sizes, int n_in,
                              void* d_out, int out_size, void* d_ws, size_t ws_size,
                              hipStream_t stream) {
  const float* x  = (const float*)d_in[0];
  const float* Wq = (const float*)d_in[1];
  const float* bq = (const float*)d_in[2];
  const float* Wk = (const float*)d_in[3];
  const float* bk = (const float*)d_in[4];
  const float* Wv = (const float*)d_in[5];
  const float* bv = (const float*)d_in[6];
  const float* Wp = (const float*)d_in[7];
  const float* bp = (const float*)d_in[8];
  float* out = (float*)d_out;

  u16* ws    = (u16*)d_ws;
  u16* xb    = ws;                       // 4,194,304  (x as bf16)
  u16* wqb   = xb   + 4194304;           // 4 x 1,048,576 contiguous
  u16* wkb   = wqb  + 1048576;
  u16* wvb   = wkb  + 1048576;
  u16* wpb   = wvb  + 1048576;
  u16* q_ws  = wpb  + 1048576;           // [B,NH,T,hd] (scaled by rs*log2e)
  u16* k_ws  = q_ws + 4194304;           // [B,NH,T,hd] (scaled by rs)
  u16* vt_ws = k_ws + 4194304;           // [B,NH,hd,T]
  u16* ao    = vt_ws + 4194304;          // [B,T,D] attention output

  cvt_bf16<<<4096, 256, 0, stream>>>(x, xb, 4194304);
  cvt_w4<<<dim3(1024, 4), 256, 0, stream>>>(Wq, Wk, Wv, Wp, wqb);

  qkv_gemm<<<dim3(DMODEL / 128, MROWS / 128, 3), 256, 0, stream>>>(
      xb, wqb, wkb, wvb, bq, bk, bv, q_ws, k_ws, vt_ws);

  attn_fused<<<dim3(T_SEQ / 64, 2 * NHEAD), 256, 0, stream>>>(q_ws, k_ws, vt_ws, ao);

  out_gemm<<<dim3(DMODEL / 128, MROWS / 128), 256, 0, stream>>>(ao, wpb, bp, out);
}